// Round 7
// baseline (138.168 us; speedup 1.0000x reference)
//
#include <hip/hip_runtime.h>
#include <math.h>

// JointAttentionMemoryBank via fp16 MFMA.  out = W @ softmax(W^T x / sqrt(D))
//   B=16 N=4096 D=128 M=1536.  fp32 in/out.
// R7: pipelined sessions. 24 sessions of 64 m, Pbuf double-buffered, ONE
// barrier per session; each segment = phase1(q) + phase2(q-1) so every
// vmcnt-drain point is amortized over 2x MFMA and W loads get a full segment
// of cover. wt prefetched one session ahead (regs); wd issued at segment top,
// consumed at bottom. LDS 36.9 KB -> 4 blocks/CU (register cap = 4 waves/SIMD,
// ~124 total VGPR+AGPR/wave). No-max softmax; P unnormalized fp16.

#define Bdim 16
#define Ndim 4096
#define Ddim 128
#define Mdim 1536
#define NT 64               // rows (n) per block
#define NTHREADS 256        // 4 waves
#define NSESS 24            // m-sessions of 64
#define XPAD 136            // xs row stride fp16
#define PPAD 72             // Pbuf row stride fp16 (64 + 8)
#define NFRAG 24576         // fragments per W array = D*M/8

typedef __attribute__((ext_vector_type(8))) _Float16 f16x8;  // 4 VGPRs
typedef __attribute__((ext_vector_type(4))) _Float16 f16x4;  // 8 B
typedef __attribute__((ext_vector_type(4))) float    f32x4;  // MFMA C/D

// ---- prep: W (D,M) fp32 -> fragment-ordered fp16 arrays (gather form) ----
// wt (phase-1 A = W^T, pre-scaled 1/sqrt(D)):
//   frag f = (mt*4 + ks)*64 + lane ; m = mt*16 + (lane&15), d = ks*32 + (lane>>4)*8 + j
// wd (phase-2 A = W):
//   frag f = (dt*48 + km)*64 + lane ; d = dt*16 + (lane&15), m = km*32 + (lane>>4)*8 + j
__global__ void jamb_prep(const float* __restrict__ w,
                          _Float16* __restrict__ wt,
                          _Float16* __restrict__ wd) {
    const int tid = blockIdx.x * 256 + threadIdx.x;   // [0, 2*NFRAG)
    const float SC = 0.08838834764831843f;            // 1/sqrt(128)
    if (tid < NFRAG) {                                // blocks 0..95: wt
        const int f    = tid;
        const int lane = f & 63;
        const int fs   = f >> 6;
        const int ks   = fs & 3;          // 0..3
        const int mt   = fs >> 2;         // 0..95
        const int m    = mt * 16 + (lane & 15);
        const int d0   = ks * 32 + (lane >> 4) * 8;
        f16x8 pk;
        #pragma unroll
        for (int j = 0; j < 8; ++j)
            pk[j] = (_Float16)(w[(size_t)(d0 + j) * Mdim + m] * SC);
        *(f16x8*)&wt[(size_t)f * 8] = pk;
    } else {                                          // blocks 96..191: wd
        const int f    = tid - NFRAG;
        const int lane = f & 63;
        const int fs   = f >> 6;
        const int km   = fs % 48;         // 0..47
        const int dt   = fs / 48;         // 0..7
        const int d    = dt * 16 + (lane & 15);
        const int m0   = km * 32 + (lane >> 4) * 8;
        const float* src = w + (size_t)d * Mdim + m0;
        const float4 v0 = *(const float4*)src;
        const float4 v1 = *(const float4*)(src + 4);
        f16x8 pk;
        pk[0] = (_Float16)v0.x; pk[1] = (_Float16)v0.y;
        pk[2] = (_Float16)v0.z; pk[3] = (_Float16)v0.w;
        pk[4] = (_Float16)v1.x; pk[5] = (_Float16)v1.y;
        pk[6] = (_Float16)v1.z; pk[7] = (_Float16)v1.w;
        *(f16x8*)&wd[(size_t)f * 8] = pk;
    }
}

__global__ __launch_bounds__(NTHREADS, 4)
void jamb_mfma_kernel(const float* __restrict__ x,
                      const _Float16* __restrict__ wt,
                      const _Float16* __restrict__ wd,
                      float* __restrict__ out) {
    __shared__ __align__(16) _Float16 xs[NT * XPAD];       // 17408 B
    __shared__ __align__(16) _Float16 Pbuf[2][NT * PPAD];  // 2 x 9216 B
    __shared__ float redsum[4][4][16];                     // 1024 B  (total 36864 B)

    const int t    = threadIdx.x;
    const int w    = t >> 6;        // wave 0..3
    const int l    = t & 63;
    const int c16  = l & 15;
    const int quad = l >> 4;

    const int blk   = blockIdx.x;
    const int b     = blk >> 6;             // 64 blocks per batch
    const int nbase = (blk & 63) * NT;

    // ---- stage x tile -> LDS fp16 (coalesced float4 reads) ----
    {
        const float* xb = x + (size_t)(b * Ndim + nbase) * Ddim;
        #pragma unroll
        for (int i = 0; i < 8; ++i) {
            const int f   = t + i * 256;        // float4 index, [0,2048)
            const int row = f >> 5;             // 32 float4 per row
            const int c4  = (f & 31) * 4;
            const float4 v = *(const float4*)(xb + row * Ddim + c4);
            f16x4 pk;
            pk[0] = (_Float16)v.x; pk[1] = (_Float16)v.y;
            pk[2] = (_Float16)v.z; pk[3] = (_Float16)v.w;
            *(f16x4*)&xs[row * XPAD + c4] = pk;
        }
    }
    __syncthreads();

    const f16x8* WT = (const f16x8*)wt;
    const f16x8* WD = (const f16x8*)wd;

    float sums[4] = {0.f, 0.f, 0.f, 0.f};        // per n-tile unnormalized softmax sums
    f32x4 c[2][4];                               // phase-2 acc: 2 d-tiles x 4 n-tiles
    #pragma unroll
    for (int i = 0; i < 2; ++i)
        #pragma unroll
        for (int nt = 0; nt < 4; ++nt) c[i][nt] = (f32x4){0.f, 0.f, 0.f, 0.f};

    // wt fragments for session 0 (wave owns mtile q*4 + w each session)
    f16x8 wtf[4];
    #pragma unroll
    for (int s = 0; s < 4; ++s) wtf[s] = WT[((0 * 4 + w) * 4 + s) * 64 + l];

    #pragma unroll 1
    for (int q = 0; q < NSESS; ++q) {
        const int bq = q & 1;

        // ---- prefetch next session's wt (registers) ----
        f16x8 wtn[4];
        {
            const int mtn = (q + 1 < NSESS ? (q + 1) * 4 + w : q * 4 + w);
            #pragma unroll
            for (int s = 0; s < 4; ++s) wtn[s] = WT[(mtn * 4 + s) * 64 + l];
        }
        // ---- issue wd loads for phase2(q-1) (consumed at segment bottom) ----
        f16x8 wdv[2][2];
        if (q) {
            #pragma unroll
            for (int dt2 = 0; dt2 < 2; ++dt2)
                #pragma unroll
                for (int ks = 0; ks < 2; ++ks)
                    wdv[dt2][ks] = WD[((2 * w + dt2) * 48 + (q - 1) * 2 + ks) * 64 + l];
        }

        // ---- phase 1(q): 1 m-tile x 4 n-tiles, K=128 ----
        f32x4 a1[4];
        #pragma unroll
        for (int nt = 0; nt < 4; ++nt) a1[nt] = (f32x4){0.f, 0.f, 0.f, 0.f};
        #pragma unroll
        for (int s = 0; s < 4; ++s) {
            #pragma unroll
            for (int nt = 0; nt < 4; ++nt) {
                const f16x8 bx = *(const f16x8*)&xs[(nt * 16 + c16) * XPAD + s * 32 + quad * 8];
                a1[nt] = __builtin_amdgcn_mfma_f32_16x16x32_f16(wtf[s], bx, a1[nt], 0, 0, 0);
            }
        }

        // ---- exp + P write into Pbuf[bq] (session-local m = w*16 + quad*4) ----
        #pragma unroll
        for (int nt = 0; nt < 4; ++nt) {
            const float e0 = __expf(a1[nt][0]);
            const float e1 = __expf(a1[nt][1]);
            const float e2 = __expf(a1[nt][2]);
            const float e3 = __expf(a1[nt][3]);
            sums[nt] += (e0 + e1) + (e2 + e3);
            f16x4 pk;
            pk[0] = (_Float16)e0; pk[1] = (_Float16)e1;
            pk[2] = (_Float16)e2; pk[3] = (_Float16)e3;
            *(f16x4*)&Pbuf[bq][(nt * 16 + c16) * PPAD + w * 16 + quad * 4] = pk;
        }

        // ---- phase 2(q-1): 2 d-tiles x 2 ksteps x 4 n-tiles from Pbuf[1-bq] ----
        if (q) {
            #pragma unroll
            for (int ks = 0; ks < 2; ++ks) {
                #pragma unroll
                for (int nt = 0; nt < 4; ++nt) {
                    const f16x8 p = *(const f16x8*)&Pbuf[1 - bq][(nt * 16 + c16) * PPAD + ks * 32 + quad * 8];
                    c[0][nt] = __builtin_amdgcn_mfma_f32_16x16x32_f16(wdv[0][ks], p, c[0][nt], 0, 0, 0);
                    c[1][nt] = __builtin_amdgcn_mfma_f32_16x16x32_f16(wdv[1][ks], p, c[1][nt], 0, 0, 0);
                }
            }
        }

        __syncthreads();   // publishes P(q); P(q-1) reads complete
        #pragma unroll
        for (int s = 0; s < 4; ++s) wtf[s] = wtn[s];
    }

    // ---- tail: phase 2 for session 23 (Pbuf[1], published by last barrier) ----
    {
        f16x8 wdv[2][2];
        #pragma unroll
        for (int dt2 = 0; dt2 < 2; ++dt2)
            #pragma unroll
            for (int ks = 0; ks < 2; ++ks)
                wdv[dt2][ks] = WD[((2 * w + dt2) * 48 + (NSESS - 1) * 2 + ks) * 64 + l];
        #pragma unroll
        for (int ks = 0; ks < 2; ++ks) {
            #pragma unroll
            for (int nt = 0; nt < 4; ++nt) {
                const f16x8 p = *(const f16x8*)&Pbuf[1][(nt * 16 + c16) * PPAD + ks * 32 + quad * 8];
                c[0][nt] = __builtin_amdgcn_mfma_f32_16x16x32_f16(wdv[0][ks], p, c[0][nt], 0, 0, 0);
                c[1][nt] = __builtin_amdgcn_mfma_f32_16x16x32_f16(wdv[1][ks], p, c[1][nt], 0, 0, 0);
            }
        }
    }

    // ---- softmax sums: cross-quad butterfly, cross-wave via LDS ----
    #pragma unroll
    for (int nt = 0; nt < 4; ++nt) {
        sums[nt] += __shfl_xor(sums[nt], 16, 64);
        sums[nt] += __shfl_xor(sums[nt], 32, 64);
    }
    if (quad == 0) {
        #pragma unroll
        for (int nt = 0; nt < 4; ++nt) redsum[w][nt][c16] = sums[nt];
    }
    __syncthreads();

    float inv[4];
    #pragma unroll
    for (int nt = 0; nt < 4; ++nt)
        inv[nt] = 1.f / ((redsum[0][nt][c16] + redsum[1][nt][c16]) +
                         (redsum[2][nt][c16] + redsum[3][nt][c16]));

    // ---- epilogue: C row = d-in-tile = quad*4+reg, col n = c16 ----
    #pragma unroll
    for (int dt2 = 0; dt2 < 2; ++dt2) {
        #pragma unroll
        for (int nt = 0; nt < 4; ++nt) {
            float* op = out + (size_t)(b * Ndim + nbase + nt * 16 + c16) * Ddim
                           + (2 * w + dt2) * 16 + quad * 4;
            float4 o;
            o.x = c[dt2][nt][0] * inv[nt];
            o.y = c[dt2][nt][1] * inv[nt];
            o.z = c[dt2][nt][2] * inv[nt];
            o.w = c[dt2][nt][3] * inv[nt];
            *(float4*)op = o;
        }
    }
}

extern "C" void kernel_launch(void* const* d_in, const int* in_sizes, int n_in,
                              void* d_out, int out_size, void* d_ws, size_t ws_size,
                              hipStream_t stream) {
    const float* x = (const float*)d_in[0];   // (B,N,D)
    const float* w = (const float*)d_in[1];   // (1,D,M)
    float* out = (float*)d_out;
    (void)in_sizes; (void)n_in; (void)out_size; (void)ws_size;

    _Float16* wt = (_Float16*)d_ws;           // 384 KB
    _Float16* wd = wt + Ddim * Mdim;          // 384 KB

    jamb_prep<<<dim3((2 * NFRAG) / 256), dim3(256), 0, stream>>>(w, wt, wd);  // 192 blocks
    jamb_mfma_kernel<<<dim3((Bdim * Ndim) / NT), dim3(NTHREADS), 0, stream>>>(x, wt, wd, out);
}